// Round 2
// baseline (142.863 us; speedup 1.0000x reference)
//
#include <hip/hip_runtime.h>
#include <hip/hip_cooperative_groups.h>
#include <hip/hip_bf16.h>
#include <math.h>

namespace cg = cooperative_groups;

// out = colsum( tanh( relu( relu(S@W1+b1)@W2+b2 )@Wq+bq ) ) @ Wh + bh
// (graph stage is a no-op: all edge weights 1.0 => mean_w == 1.0 everywhere)
//
// Round 9: single cooperative kernel. Phase 0: all 256 blocks repack the
// weights into MFMA-fragment order (104 items/block) while ALSO staging their
// own 32x512 S strip into LDS (prep latency hides the S HBM read). grid.sync.
// Phase 1: the barrier-free fragment-direct chain from round 8. Removes one
// kernel launch gap and shrinks prep wall time ~5x.

#define N_ROWS 8192
#define F_IN   512
#define H_DIM  256
#define W_DIM  64

#define LDS_S 520   // S-plane leading dim (bf16): 1040 B stride == 4 banks mod 32 (free)
#define LDE   264   // E-plane leading dim:  528 B stride == 4 banks mod 32 (free)

// fragment-ordered weight planes: frag id = (n16*(K/32) + ks), 64 lanes x 8 bf16
#define W1_FRAGS (16 * 16 * 64)   // n16 x ks x lane items
#define W2_FRAGS (16 * 8 * 64)
#define WQ_FRAGS (4 * 8 * 64)
#define PREP_T   (W1_FRAGS + W2_FRAGS + WQ_FRAGS)
#define PREP_PER_BLK ((PREP_T + 255) / 256)   // 104 items per block

using bf16x8 = __attribute__((ext_vector_type(8))) short;
using bf16x4 = __attribute__((ext_vector_type(4))) short;
using f32x4  = __attribute__((ext_vector_type(4))) float;
typedef __hip_bfloat16 bf16;

__device__ __forceinline__ void split2(float v, bf16& hi, bf16& lo) {
    bf16 h = __float2bfloat16(v);
    hi = h;
    lo = __float2bfloat16(v - __bfloat162float(h));
}

// ---- fused everything: prep + S-stage | grid.sync | chain ----
// 512 threads = 8 waves. gemm1/2: wave w -> cols 32w..32w+32 (jj = 2 col-frags)
// x 2 row-frags. gemm3: wave w -> row-frag w>>2, col-frag w&3.
__global__ __launch_bounds__(512) void fused_all(
    const float* __restrict__ S,
    const float* __restrict__ W1, const float* __restrict__ W2,
    const float* __restrict__ Wq,
    const float* __restrict__ b1, const float* __restrict__ b2,
    const float* __restrict__ bq, const float* __restrict__ Wh,
    const float* __restrict__ bh,
    bf16* __restrict__ W1h, bf16* __restrict__ W1l,
    bf16* __restrict__ W2h, bf16* __restrict__ W2l,
    bf16* __restrict__ Wqh, bf16* __restrict__ Wql,
    float* __restrict__ out)
{
    __shared__ bf16 Ssh[32 * LDS_S];        // full 32 x 512 S strip, hi plane
    __shared__ bf16 Ssl[32 * LDS_S];        // lo plane
    __shared__ bf16 E1h[32 * LDE];
    __shared__ bf16 E1l[32 * LDE];
    __shared__ bf16 E2h[32 * LDE];
    __shared__ bf16 E2l[32 * LDE];
    __shared__ float red[2][64];

    const int t = threadIdx.x;
    const int lane = t & 63;
    const int w = t >> 6, quad = lane >> 4, m16 = t & 15;
    const int row0 = blockIdx.x * 32;

    if (blockIdx.x == 0 && t == 0) out[0] = bh[0];

    // ---- phase 0a: weight repack, 104 fragment-lane items per block ----
    // layout: plane[((n16*(K/32)+ks)*64+lane)*8+j] = W[ks*32+(lane>>4)*8+j][n16*16+(lane&15)]
    if (t < PREP_PER_BLK) {
        int item = blockIdx.x * PREP_PER_BLK + t;
        if (item < W1_FRAGS) {                        // W1 [512][256], K/32 = 16
            const int l = item & 63, ks = (item >> 6) & 15, n16 = item >> 10;
            const int n = n16 * 16 + (l & 15);
            const int kb = ks * 32 + ((l >> 4) << 3);
            bf16 hb[8], lb[8];
            #pragma unroll
            for (int j = 0; j < 8; ++j)
                split2(W1[(size_t)(kb + j) * H_DIM + n], hb[j], lb[j]);
            *(bf16x8*)(W1h + (size_t)item * 8) = *(const bf16x8*)hb;
            *(bf16x8*)(W1l + (size_t)item * 8) = *(const bf16x8*)lb;
        } else if (item < W1_FRAGS + W2_FRAGS) {      // W2 [256][256], K/32 = 8
            const int it = item - W1_FRAGS;
            const int l = it & 63, ks = (it >> 6) & 7, n16 = it >> 9;
            const int n = n16 * 16 + (l & 15);
            const int kb = ks * 32 + ((l >> 4) << 3);
            bf16 hb[8], lb[8];
            #pragma unroll
            for (int j = 0; j < 8; ++j)
                split2(W2[(size_t)(kb + j) * H_DIM + n], hb[j], lb[j]);
            *(bf16x8*)(W2h + (size_t)it * 8) = *(const bf16x8*)hb;
            *(bf16x8*)(W2l + (size_t)it * 8) = *(const bf16x8*)lb;
        } else if (item < PREP_T) {                   // Wq [256][64], K/32 = 8
            const int it = item - W1_FRAGS - W2_FRAGS;
            const int l = it & 63, ks = (it >> 6) & 7, n16 = it >> 9;
            const int n = n16 * 16 + (l & 15);
            const int kb = ks * 32 + ((l >> 4) << 3);
            bf16 hb[8], lb[8];
            #pragma unroll
            for (int j = 0; j < 8; ++j)
                split2(Wq[(size_t)(kb + j) * W_DIM + n], hb[j], lb[j]);
            *(bf16x8*)(Wqh + (size_t)it * 8) = *(const bf16x8*)hb;
            *(bf16x8*)(Wql + (size_t)it * 8) = *(const bf16x8*)lb;
        }
    }

    // ---- phase 0b: stage full S strip (overlaps prep latency) ----
    #pragma unroll
    for (int i = 0; i < 8; ++i) {
        const int idx = i * 2048 + t * 4;            // coalesced float4
        const int r = idx >> 9, c = idx & 511;
        float4 sv = *(const float4*)(S + (size_t)(row0 + r) * F_IN + c);
        bf16 hb[4], lb[4];
        split2(sv.x, hb[0], lb[0]); split2(sv.y, hb[1], lb[1]);
        split2(sv.z, hb[2], lb[2]); split2(sv.w, hb[3], lb[3]);
        *(bf16x4*)&Ssh[r * LDS_S + c] = *(const bf16x4*)hb;
        *(bf16x4*)&Ssl[r * LDS_S + c] = *(const bf16x4*)lb;
    }

    cg::this_grid().sync();    // weights published (device scope) + S staged

    // ================= GEMM1: E1 = relu(S @ W1^T + b1) =================
    f32x4 acc[2][2] = {};
    #pragma unroll
    for (int ks = 0; ks < F_IN / 32; ++ks) {
        const int ao = ks * 32 + quad * 8;
        bf16x8 a0h = *(const bf16x8*)&Ssh[m16 * LDS_S + ao];
        bf16x8 a0l = *(const bf16x8*)&Ssl[m16 * LDS_S + ao];
        bf16x8 a1h = *(const bf16x8*)&Ssh[(16 + m16) * LDS_S + ao];
        bf16x8 a1l = *(const bf16x8*)&Ssl[(16 + m16) * LDS_S + ao];
        #pragma unroll
        for (int jj = 0; jj < 2; ++jj) {
            const size_t off = ((size_t)(((2 * w + jj) * 16 + ks) * 64 + lane)) * 8;
            bf16x8 b_h = *(const bf16x8*)(W1h + off);
            bf16x8 b_l = *(const bf16x8*)(W1l + off);
            acc[0][jj] = __builtin_amdgcn_mfma_f32_16x16x32_bf16(a0h, b_h, acc[0][jj], 0, 0, 0);
            acc[0][jj] = __builtin_amdgcn_mfma_f32_16x16x32_bf16(a0l, b_h, acc[0][jj], 0, 0, 0);
            acc[0][jj] = __builtin_amdgcn_mfma_f32_16x16x32_bf16(a0h, b_l, acc[0][jj], 0, 0, 0);
            acc[1][jj] = __builtin_amdgcn_mfma_f32_16x16x32_bf16(a1h, b_h, acc[1][jj], 0, 0, 0);
            acc[1][jj] = __builtin_amdgcn_mfma_f32_16x16x32_bf16(a1l, b_h, acc[1][jj], 0, 0, 0);
            acc[1][jj] = __builtin_amdgcn_mfma_f32_16x16x32_bf16(a1h, b_l, acc[1][jj], 0, 0, 0);
        }
    }
    // epilogue: relu + bias -> E1 hi/lo (LDS)
    #pragma unroll
    for (int i = 0; i < 2; ++i)
        #pragma unroll
        for (int jj = 0; jj < 2; ++jj) {
            const int c = 32 * w + jj * 16 + m16;
            const float bv = b1[c];
            #pragma unroll
            for (int r = 0; r < 4; ++r) {
                const int rr = i * 16 + quad * 4 + r;
                float vv = fmaxf(acc[i][jj][r] + bv, 0.0f);
                split2(vv, E1h[rr * LDE + c], E1l[rr * LDE + c]);
            }
        }
    __syncthreads();                                 // E1 ready

    // ================= GEMM2: E2 = relu(E1 @ W2^T + b2) =================
    #pragma unroll
    for (int i = 0; i < 2; ++i)
        #pragma unroll
        for (int jj = 0; jj < 2; ++jj)
            acc[i][jj] = (f32x4){0.f, 0.f, 0.f, 0.f};
    #pragma unroll
    for (int ks = 0; ks < H_DIM / 32; ++ks) {
        const int ao = ks * 32 + quad * 8;
        bf16x8 a0h = *(const bf16x8*)&E1h[m16 * LDE + ao];
        bf16x8 a0l = *(const bf16x8*)&E1l[m16 * LDE + ao];
        bf16x8 a1h = *(const bf16x8*)&E1h[(16 + m16) * LDE + ao];
        bf16x8 a1l = *(const bf16x8*)&E1l[(16 + m16) * LDE + ao];
        #pragma unroll
        for (int jj = 0; jj < 2; ++jj) {
            const size_t off = ((size_t)(((2 * w + jj) * 8 + ks) * 64 + lane)) * 8;
            bf16x8 b_h = *(const bf16x8*)(W2h + off);
            bf16x8 b_l = *(const bf16x8*)(W2l + off);
            acc[0][jj] = __builtin_amdgcn_mfma_f32_16x16x32_bf16(a0h, b_h, acc[0][jj], 0, 0, 0);
            acc[0][jj] = __builtin_amdgcn_mfma_f32_16x16x32_bf16(a0l, b_h, acc[0][jj], 0, 0, 0);
            acc[0][jj] = __builtin_amdgcn_mfma_f32_16x16x32_bf16(a0h, b_l, acc[0][jj], 0, 0, 0);
            acc[1][jj] = __builtin_amdgcn_mfma_f32_16x16x32_bf16(a1h, b_h, acc[1][jj], 0, 0, 0);
            acc[1][jj] = __builtin_amdgcn_mfma_f32_16x16x32_bf16(a1l, b_h, acc[1][jj], 0, 0, 0);
            acc[1][jj] = __builtin_amdgcn_mfma_f32_16x16x32_bf16(a1h, b_l, acc[1][jj], 0, 0, 0);
        }
    }
    #pragma unroll
    for (int i = 0; i < 2; ++i)
        #pragma unroll
        for (int jj = 0; jj < 2; ++jj) {
            const int c = 32 * w + jj * 16 + m16;
            const float bv = b2[c];
            #pragma unroll
            for (int r = 0; r < 4; ++r) {
                const int rr = i * 16 + quad * 4 + r;
                float vv = fmaxf(acc[i][jj][r] + bv, 0.0f);
                split2(vv, E2h[rr * LDE + c], E2l[rr * LDE + c]);
            }
        }
    __syncthreads();                                 // E2 ready

    // ====== GEMM3 + tanh + colsum + dot(Wh): atomicAdd one scalar ======
    {
        const int rf = w >> 2, cf = w & 3;
        f32x4 acc3 = {0.f, 0.f, 0.f, 0.f};
        #pragma unroll
        for (int ks = 0; ks < H_DIM / 32; ++ks) {
            const int ao = ks * 32 + quad * 8;
            bf16x8 a_h = *(const bf16x8*)&E2h[(rf * 16 + m16) * LDE + ao];
            bf16x8 a_l = *(const bf16x8*)&E2l[(rf * 16 + m16) * LDE + ao];
            const size_t off = ((size_t)((cf * 8 + ks) * 64 + lane)) * 8;
            bf16x8 b_h = *(const bf16x8*)(Wqh + off);
            bf16x8 b_l = *(const bf16x8*)(Wql + off);
            acc3 = __builtin_amdgcn_mfma_f32_16x16x32_bf16(a_h, b_h, acc3, 0, 0, 0);
            acc3 = __builtin_amdgcn_mfma_f32_16x16x32_bf16(a_l, b_h, acc3, 0, 0, 0);
            acc3 = __builtin_amdgcn_mfma_f32_16x16x32_bf16(a_h, b_l, acc3, 0, 0, 0);
        }
        const int c = cf * 16 + m16;
        const float bv = bq[c];
        float v = 0.f;
        #pragma unroll
        for (int r = 0; r < 4; ++r)
            v += tanhf(acc3[r] + bv);
        v += __shfl_xor(v, 16, 64);       // sum rows within row-frag
        v += __shfl_xor(v, 32, 64);
        if (quad == 0) red[rf][c] = v;    // (rf,cf) waves write disjoint cols
        __syncthreads();
        if (t < W_DIM) {
            float s = (red[0][t] + red[1][t]) * Wh[t];
            #pragma unroll
            for (int o = 32; o > 0; o >>= 1) s += __shfl_down(s, o);
            if (t == 0) atomicAdd(out, s);
        }
    }
}

extern "C" void kernel_launch(void* const* d_in, const int* in_sizes, int n_in,
                              void* d_out, int out_size, void* d_ws, size_t ws_size,
                              hipStream_t stream) {
    const float* state = (const float*)d_in[0];
    const float* W1    = (const float*)d_in[1];
    const float* b1    = (const float*)d_in[2];
    const float* W2    = (const float*)d_in[3];
    const float* b2    = (const float*)d_in[4];
    const float* Wq    = (const float*)d_in[5];
    const float* bq    = (const float*)d_in[6];
    const float* Wh    = (const float*)d_in[7];
    const float* bh    = (const float*)d_in[8];

    bf16* p = (bf16*)d_ws;
    bf16* W1h = p; p += (size_t)H_DIM * F_IN;
    bf16* W1l = p; p += (size_t)H_DIM * F_IN;
    bf16* W2h = p; p += (size_t)H_DIM * H_DIM;
    bf16* W2l = p; p += (size_t)H_DIM * H_DIM;
    bf16* Wqh = p; p += (size_t)W_DIM * H_DIM;
    bf16* Wql = p; p += (size_t)W_DIM * H_DIM;
    float* outp = (float*)d_out;

    void* args[] = {
        (void*)&state, (void*)&W1, (void*)&W2, (void*)&Wq,
        (void*)&b1, (void*)&b2, (void*)&bq, (void*)&Wh, (void*)&bh,
        (void*)&W1h, (void*)&W1l, (void*)&W2h, (void*)&W2l,
        (void*)&Wqh, (void*)&Wql, (void*)&outp};

    hipLaunchCooperativeKernel((void*)fused_all, dim3(N_ROWS / 32), dim3(512),
                               args, 0, stream);
}

// Round 3
// 96.184 us; speedup vs baseline: 1.4853x; 1.4853x over previous
//
#include <hip/hip_runtime.h>
#include <hip/hip_bf16.h>
#include <math.h>

// out = colsum( tanh( relu( relu(S@W1+b1)@W2+b2 )@Wq+bq ) ) @ Wh + bh
// (graph stage is a no-op: all edge weights 1.0 => mean_w == 1.0 everywhere)
//
// Round 10: revert cooperative experiment (grid.sync cost ~40us on 8 XCDs).
// Back to round-8 two-kernel structure (prep repack -> fragment-direct chain),
// plus depth-3 register-ring prefetch of weight fragments: L2 latency (~400cy)
// now covered by 3 stages of in-flight loads + barrier-drain overlap, instead
// of stalling each 6-MFMA group on vmcnt.

#define N_ROWS 8192
#define F_IN   512
#define H_DIM  256
#define W_DIM  64

#define LDS_S 520   // S-plane leading dim (bf16): 1040 B stride == 4 banks mod 32 (free)
#define LDE   264   // E-plane leading dim:  528 B stride == 4 banks mod 32 (free)

// fragment-ordered weight planes: frag id = (n16*(K/32) + ks), 64 lanes x 8 bf16
#define W1_FRAGS (16 * 16 * 64)   // n16 x ks x lane threads
#define W2_FRAGS (16 * 8 * 64)
#define WQ_FRAGS (4 * 8 * 64)
#define PREP_T   (W1_FRAGS + W2_FRAGS + WQ_FRAGS)
#define PREP_BLOCKS ((PREP_T + 255) / 256)

using bf16x8 = __attribute__((ext_vector_type(8))) short;
using bf16x4 = __attribute__((ext_vector_type(4))) short;
using f32x4  = __attribute__((ext_vector_type(4))) float;
typedef __hip_bfloat16 bf16;

__device__ __forceinline__ void split2(float v, bf16& hi, bf16& lo) {
    bf16 h = __float2bfloat16(v);
    hi = h;
    lo = __float2bfloat16(v - __bfloat162float(h));
}

// ---- weight split + repack into MFMA fragment order; out = bh ----
// layout: plane[((n16*(K/32)+ks)*64+lane)*8+j] = W[ks*32+(lane>>4)*8+j][n16*16+(lane&15)]
__global__ __launch_bounds__(256) void prep_w(
    const float* __restrict__ W1, const float* __restrict__ W2,
    const float* __restrict__ Wq, const float* __restrict__ bh,
    bf16* __restrict__ W1h, bf16* __restrict__ W1l,
    bf16* __restrict__ W2h, bf16* __restrict__ W2l,
    bf16* __restrict__ Wqh, bf16* __restrict__ Wql,
    float* __restrict__ out)
{
    if (blockIdx.x == 0 && threadIdx.x == 0) out[0] = bh[0];
    int gid = blockIdx.x * 256 + threadIdx.x;
    if (gid < W1_FRAGS) {                         // W1 [512][256], K/32 = 16
        const int l = gid & 63, ks = (gid >> 6) & 15, n16 = gid >> 10;
        const int n = n16 * 16 + (l & 15);
        const int kb = ks * 32 + ((l >> 4) << 3);
        bf16 hb[8], lb[8];
        #pragma unroll
        for (int j = 0; j < 8; ++j)
            split2(W1[(size_t)(kb + j) * H_DIM + n], hb[j], lb[j]);
        *(bf16x8*)(W1h + (size_t)gid * 8) = *(const bf16x8*)hb;
        *(bf16x8*)(W1l + (size_t)gid * 8) = *(const bf16x8*)lb;
        return;
    }
    gid -= W1_FRAGS;
    if (gid < W2_FRAGS) {                         // W2 [256][256], K/32 = 8
        const int l = gid & 63, ks = (gid >> 6) & 7, n16 = gid >> 9;
        const int n = n16 * 16 + (l & 15);
        const int kb = ks * 32 + ((l >> 4) << 3);
        bf16 hb[8], lb[8];
        #pragma unroll
        for (int j = 0; j < 8; ++j)
            split2(W2[(size_t)(kb + j) * H_DIM + n], hb[j], lb[j]);
        *(bf16x8*)(W2h + (size_t)gid * 8) = *(const bf16x8*)hb;
        *(bf16x8*)(W2l + (size_t)gid * 8) = *(const bf16x8*)lb;
        return;
    }
    gid -= W2_FRAGS;
    if (gid < WQ_FRAGS) {                         // Wq [256][64], K/32 = 8
        const int l = gid & 63, ks = (gid >> 6) & 7, n16 = gid >> 9;
        const int n = n16 * 16 + (l & 15);
        const int kb = ks * 32 + ((l >> 4) << 3);
        bf16 hb[8], lb[8];
        #pragma unroll
        for (int j = 0; j < 8; ++j)
            split2(Wq[(size_t)(kb + j) * W_DIM + n], hb[j], lb[j]);
        *(bf16x8*)(Wqh + (size_t)gid * 8) = *(const bf16x8*)hb;
        *(bf16x8*)(Wql + (size_t)gid * 8) = *(const bf16x8*)lb;
    }
}

// ---- fused: 32-row strip, whole chain in one block, fragment-direct B ----
// 512 threads = 8 waves. gemm1/2: wave w -> cols 32w..32w+32 (jj = 2 col-frags)
// x 2 row-frags. gemm3: wave w -> row-frag w>>2, col-frag w&3.
// Weight fragments stream from L2 through a depth-3 register ring.
__global__ __launch_bounds__(512) void fused_chain(
    const float* __restrict__ S,
    const bf16* __restrict__ W1h, const bf16* __restrict__ W1l,
    const bf16* __restrict__ W2h, const bf16* __restrict__ W2l,
    const bf16* __restrict__ Wqh, const bf16* __restrict__ Wql,
    const float* __restrict__ b1, const float* __restrict__ b2,
    const float* __restrict__ bq, const float* __restrict__ Wh,
    float* __restrict__ out)
{
    __shared__ bf16 Ssh[32 * LDS_S];        // full 32 x 512 S strip, hi plane
    __shared__ bf16 Ssl[32 * LDS_S];        // lo plane
    __shared__ bf16 E1h[32 * LDE];
    __shared__ bf16 E1l[32 * LDE];
    __shared__ bf16 E2h[32 * LDE];
    __shared__ bf16 E2l[32 * LDE];
    __shared__ float red[2][64];

    const int t = threadIdx.x;
    const int lane = t & 63;
    const int w = t >> 6, quad = lane >> 4, m16 = t & 15;
    const int row0 = blockIdx.x * 32;

    // ---- stage full S strip once (32 x 512 fp32 -> split bf16 LDS) ----
    #pragma unroll
    for (int i = 0; i < 8; ++i) {
        const int idx = i * 2048 + t * 4;            // coalesced float4
        const int r = idx >> 9, c = idx & 511;
        float4 sv = *(const float4*)(S + (size_t)(row0 + r) * F_IN + c);
        bf16 hb[4], lb[4];
        split2(sv.x, hb[0], lb[0]); split2(sv.y, hb[1], lb[1]);
        split2(sv.z, hb[2], lb[2]); split2(sv.w, hb[3], lb[3]);
        *(bf16x4*)&Ssh[r * LDS_S + c] = *(const bf16x4*)hb;
        *(bf16x4*)&Ssl[r * LDS_S + c] = *(const bf16x4*)lb;
    }

    // ================= GEMM1: E1 = relu(S @ W1^T + b1) =================
    f32x4 acc[2][2] = {};
    {
        bf16x8 rh[4][2], rl[4][2];                  // depth-3 ring (4 slots)
        #pragma unroll
        for (int p = 0; p < 3; ++p)                 // issued BEFORE the barrier:
            #pragma unroll
            for (int jj = 0; jj < 2; ++jj) {        // latency drains under it
                const size_t off = ((size_t)(((2 * w + jj) * 16 + p) * 64 + lane)) * 8;
                rh[p][jj] = *(const bf16x8*)(W1h + off);
                rl[p][jj] = *(const bf16x8*)(W1l + off);
            }
        __syncthreads();                            // S strip ready
        #pragma unroll
        for (int ks = 0; ks < 16; ++ks) {
            const int cur = ks & 3;
            if (ks + 3 < 16) {
                const int nx = (ks + 3) & 3;
                #pragma unroll
                for (int jj = 0; jj < 2; ++jj) {
                    const size_t off = ((size_t)(((2 * w + jj) * 16 + ks + 3) * 64 + lane)) * 8;
                    rh[nx][jj] = *(const bf16x8*)(W1h + off);
                    rl[nx][jj] = *(const bf16x8*)(W1l + off);
                }
            }
            const int ao = ks * 32 + quad * 8;
            bf16x8 a0h = *(const bf16x8*)&Ssh[m16 * LDS_S + ao];
            bf16x8 a0l = *(const bf16x8*)&Ssl[m16 * LDS_S + ao];
            bf16x8 a1h = *(const bf16x8*)&Ssh[(16 + m16) * LDS_S + ao];
            bf16x8 a1l = *(const bf16x8*)&Ssl[(16 + m16) * LDS_S + ao];
            #pragma unroll
            for (int jj = 0; jj < 2; ++jj) {
                bf16x8 b_h = rh[cur][jj], b_l = rl[cur][jj];
                acc[0][jj] = __builtin_amdgcn_mfma_f32_16x16x32_bf16(a0h, b_h, acc[0][jj], 0, 0, 0);
                acc[0][jj] = __builtin_amdgcn_mfma_f32_16x16x32_bf16(a0l, b_h, acc[0][jj], 0, 0, 0);
                acc[0][jj] = __builtin_amdgcn_mfma_f32_16x16x32_bf16(a0h, b_l, acc[0][jj], 0, 0, 0);
                acc[1][jj] = __builtin_amdgcn_mfma_f32_16x16x32_bf16(a1h, b_h, acc[1][jj], 0, 0, 0);
                acc[1][jj] = __builtin_amdgcn_mfma_f32_16x16x32_bf16(a1l, b_h, acc[1][jj], 0, 0, 0);
                acc[1][jj] = __builtin_amdgcn_mfma_f32_16x16x32_bf16(a1h, b_l, acc[1][jj], 0, 0, 0);
            }
        }
    }
    // epilogue: relu + bias -> E1 hi/lo (LDS)
    #pragma unroll
    for (int i = 0; i < 2; ++i)
        #pragma unroll
        for (int jj = 0; jj < 2; ++jj) {
            const int c = 32 * w + jj * 16 + m16;
            const float bv = b1[c];
            #pragma unroll
            for (int r = 0; r < 4; ++r) {
                const int rr = i * 16 + quad * 4 + r;
                float vv = fmaxf(acc[i][jj][r] + bv, 0.0f);
                split2(vv, E1h[rr * LDE + c], E1l[rr * LDE + c]);
            }
        }

    // ================= GEMM2: E2 = relu(E1 @ W2^T + b2) =================
    {
        bf16x8 rh[4][2], rl[4][2];
        #pragma unroll
        for (int p = 0; p < 3; ++p)                 // hoisted above barrier
            #pragma unroll
            for (int jj = 0; jj < 2; ++jj) {
                const size_t off = ((size_t)(((2 * w + jj) * 8 + p) * 64 + lane)) * 8;
                rh[p][jj] = *(const bf16x8*)(W2h + off);
                rl[p][jj] = *(const bf16x8*)(W2l + off);
            }
        __syncthreads();                            // E1 ready
        #pragma unroll
        for (int i = 0; i < 2; ++i)
            #pragma unroll
            for (int jj = 0; jj < 2; ++jj)
                acc[i][jj] = (f32x4){0.f, 0.f, 0.f, 0.f};
        #pragma unroll
        for (int ks = 0; ks < 8; ++ks) {
            const int cur = ks & 3;
            if (ks + 3 < 8) {
                const int nx = (ks + 3) & 3;
                #pragma unroll
                for (int jj = 0; jj < 2; ++jj) {
                    const size_t off = ((size_t)(((2 * w + jj) * 8 + ks + 3) * 64 + lane)) * 8;
                    rh[nx][jj] = *(const bf16x8*)(W2h + off);
                    rl[nx][jj] = *(const bf16x8*)(W2l + off);
                }
            }
            const int ao = ks * 32 + quad * 8;
            bf16x8 a0h = *(const bf16x8*)&E1h[m16 * LDE + ao];
            bf16x8 a0l = *(const bf16x8*)&E1l[m16 * LDE + ao];
            bf16x8 a1h = *(const bf16x8*)&E1h[(16 + m16) * LDE + ao];
            bf16x8 a1l = *(const bf16x8*)&E1l[(16 + m16) * LDE + ao];
            #pragma unroll
            for (int jj = 0; jj < 2; ++jj) {
                bf16x8 b_h = rh[cur][jj], b_l = rl[cur][jj];
                acc[0][jj] = __builtin_amdgcn_mfma_f32_16x16x32_bf16(a0h, b_h, acc[0][jj], 0, 0, 0);
                acc[0][jj] = __builtin_amdgcn_mfma_f32_16x16x32_bf16(a0l, b_h, acc[0][jj], 0, 0, 0);
                acc[0][jj] = __builtin_amdgcn_mfma_f32_16x16x32_bf16(a0h, b_l, acc[0][jj], 0, 0, 0);
                acc[1][jj] = __builtin_amdgcn_mfma_f32_16x16x32_bf16(a1h, b_h, acc[1][jj], 0, 0, 0);
                acc[1][jj] = __builtin_amdgcn_mfma_f32_16x16x32_bf16(a1l, b_h, acc[1][jj], 0, 0, 0);
                acc[1][jj] = __builtin_amdgcn_mfma_f32_16x16x32_bf16(a1h, b_l, acc[1][jj], 0, 0, 0);
            }
        }
    }
    #pragma unroll
    for (int i = 0; i < 2; ++i)
        #pragma unroll
        for (int jj = 0; jj < 2; ++jj) {
            const int c = 32 * w + jj * 16 + m16;
            const float bv = b2[c];
            #pragma unroll
            for (int r = 0; r < 4; ++r) {
                const int rr = i * 16 + quad * 4 + r;
                float vv = fmaxf(acc[i][jj][r] + bv, 0.0f);
                split2(vv, E2h[rr * LDE + c], E2l[rr * LDE + c]);
            }
        }

    // ====== GEMM3 + tanh + colsum + dot(Wh): atomicAdd one scalar ======
    {
        const int rf = w >> 2, cf = w & 3;
        bf16x8 rh[4], rl[4];
        #pragma unroll
        for (int p = 0; p < 3; ++p) {               // hoisted above barrier
            const size_t off = ((size_t)((cf * 8 + p) * 64 + lane)) * 8;
            rh[p] = *(const bf16x8*)(Wqh + off);
            rl[p] = *(const bf16x8*)(Wql + off);
        }
        __syncthreads();                            // E2 ready
        f32x4 acc3 = {0.f, 0.f, 0.f, 0.f};
        #pragma unroll
        for (int ks = 0; ks < 8; ++ks) {
            const int cur = ks & 3;
            if (ks + 3 < 8) {
                const int nx = (ks + 3) & 3;
                const size_t off = ((size_t)((cf * 8 + ks + 3) * 64 + lane)) * 8;
                rh[nx] = *(const bf16x8*)(Wqh + off);
                rl[nx] = *(const bf16x8*)(Wql + off);
            }
            const int ao = ks * 32 + quad * 8;
            bf16x8 a_h = *(const bf16x8*)&E2h[(rf * 16 + m16) * LDE + ao];
            bf16x8 a_l = *(const bf16x8*)&E2l[(rf * 16 + m16) * LDE + ao];
            acc3 = __builtin_amdgcn_mfma_f32_16x16x32_bf16(a_h, rh[cur], acc3, 0, 0, 0);
            acc3 = __builtin_amdgcn_mfma_f32_16x16x32_bf16(a_l, rh[cur], acc3, 0, 0, 0);
            acc3 = __builtin_amdgcn_mfma_f32_16x16x32_bf16(a_h, rl[cur], acc3, 0, 0, 0);
        }
        const int c = cf * 16 + m16;
        const float bv = bq[c];
        float v = 0.f;
        #pragma unroll
        for (int r = 0; r < 4; ++r)
            v += tanhf(acc3[r] + bv);
        v += __shfl_xor(v, 16, 64);       // sum rows within row-frag
        v += __shfl_xor(v, 32, 64);
        if (quad == 0) red[rf][c] = v;    // (rf,cf) waves write disjoint cols
        __syncthreads();
        if (t < W_DIM) {
            float s = (red[0][t] + red[1][t]) * Wh[t];
            #pragma unroll
            for (int o = 32; o > 0; o >>= 1) s += __shfl_down(s, o);
            if (t == 0) atomicAdd(out, s);
        }
    }
}

extern "C" void kernel_launch(void* const* d_in, const int* in_sizes, int n_in,
                              void* d_out, int out_size, void* d_ws, size_t ws_size,
                              hipStream_t stream) {
    const float* state = (const float*)d_in[0];
    const float* W1    = (const float*)d_in[1];
    const float* b1    = (const float*)d_in[2];
    const float* W2    = (const float*)d_in[3];
    const float* b2    = (const float*)d_in[4];
    const float* Wq    = (const float*)d_in[5];
    const float* bq    = (const float*)d_in[6];
    const float* Wh    = (const float*)d_in[7];
    const float* bh    = (const float*)d_in[8];

    bf16* p = (bf16*)d_ws;
    bf16* W1h = p; p += (size_t)H_DIM * F_IN;
    bf16* W1l = p; p += (size_t)H_DIM * F_IN;
    bf16* W2h = p; p += (size_t)H_DIM * H_DIM;
    bf16* W2l = p; p += (size_t)H_DIM * H_DIM;
    bf16* Wqh = p; p += (size_t)W_DIM * H_DIM;
    bf16* Wql = p; p += (size_t)W_DIM * H_DIM;

    prep_w<<<PREP_BLOCKS, 256, 0, stream>>>(
        W1, W2, Wq, bh, W1h, W1l, W2h, W2l, Wqh, Wql, (float*)d_out);

    fused_chain<<<N_ROWS / 32, 512, 0, stream>>>(
        state, W1h, W1l, W2h, W2l, Wqh, Wql, b1, b2, bq, Wh, (float*)d_out);
}

// Round 4
// 93.699 us; speedup vs baseline: 1.5247x; 1.0265x over previous
//
#include <hip/hip_runtime.h>
#include <hip/hip_bf16.h>
#include <math.h>

// out = colsum( tanh( relu( relu(S@W1+b1)@W2+b2 )@Wq+bq ) ) @ Wh + bh
// (graph stage is a no-op: all edge weights 1.0 => mean_w == 1.0 everywhere)
//
// Round 11: round-10 structure (prep repack -> fragment-direct chain with
// depth-3 register ring) + k-halved S staging: all 8 float4 loads issued up
// front, half-0 written -> barrier -> half-1 written to disjoint LDS while
// GEMM1 runs ks 0..7 -> barrier -> ks 8..15. Hides ~half of the 2.6us serial
// S-stage head under GEMM1 compute. Same k order / MFMA sequence -> absmax 0.

#define N_ROWS 8192
#define F_IN   512
#define H_DIM  256
#define W_DIM  64

#define LDS_S 520   // S-plane leading dim (bf16): 1040 B stride == 4 banks mod 32 (free)
#define LDE   264   // E-plane leading dim:  528 B stride == 4 banks mod 32 (free)

// fragment-ordered weight planes: frag id = (n16*(K/32) + ks), 64 lanes x 8 bf16
#define W1_FRAGS (16 * 16 * 64)   // n16 x ks x lane threads
#define W2_FRAGS (16 * 8 * 64)
#define WQ_FRAGS (4 * 8 * 64)
#define PREP_T   (W1_FRAGS + W2_FRAGS + WQ_FRAGS)
#define PREP_BLOCKS ((PREP_T + 255) / 256)

using bf16x8 = __attribute__((ext_vector_type(8))) short;
using bf16x4 = __attribute__((ext_vector_type(4))) short;
using f32x4  = __attribute__((ext_vector_type(4))) float;
typedef __hip_bfloat16 bf16;

__device__ __forceinline__ void split2(float v, bf16& hi, bf16& lo) {
    bf16 h = __float2bfloat16(v);
    hi = h;
    lo = __float2bfloat16(v - __bfloat162float(h));
}

// ---- weight split + repack into MFMA fragment order; out = bh ----
// layout: plane[((n16*(K/32)+ks)*64+lane)*8+j] = W[ks*32+(lane>>4)*8+j][n16*16+(lane&15)]
__global__ __launch_bounds__(256) void prep_w(
    const float* __restrict__ W1, const float* __restrict__ W2,
    const float* __restrict__ Wq, const float* __restrict__ bh,
    bf16* __restrict__ W1h, bf16* __restrict__ W1l,
    bf16* __restrict__ W2h, bf16* __restrict__ W2l,
    bf16* __restrict__ Wqh, bf16* __restrict__ Wql,
    float* __restrict__ out)
{
    if (blockIdx.x == 0 && threadIdx.x == 0) out[0] = bh[0];
    int gid = blockIdx.x * 256 + threadIdx.x;
    if (gid < W1_FRAGS) {                         // W1 [512][256], K/32 = 16
        const int l = gid & 63, ks = (gid >> 6) & 15, n16 = gid >> 10;
        const int n = n16 * 16 + (l & 15);
        const int kb = ks * 32 + ((l >> 4) << 3);
        bf16 hb[8], lb[8];
        #pragma unroll
        for (int j = 0; j < 8; ++j)
            split2(W1[(size_t)(kb + j) * H_DIM + n], hb[j], lb[j]);
        *(bf16x8*)(W1h + (size_t)gid * 8) = *(const bf16x8*)hb;
        *(bf16x8*)(W1l + (size_t)gid * 8) = *(const bf16x8*)lb;
        return;
    }
    gid -= W1_FRAGS;
    if (gid < W2_FRAGS) {                         // W2 [256][256], K/32 = 8
        const int l = gid & 63, ks = (gid >> 6) & 7, n16 = gid >> 9;
        const int n = n16 * 16 + (l & 15);
        const int kb = ks * 32 + ((l >> 4) << 3);
        bf16 hb[8], lb[8];
        #pragma unroll
        for (int j = 0; j < 8; ++j)
            split2(W2[(size_t)(kb + j) * H_DIM + n], hb[j], lb[j]);
        *(bf16x8*)(W2h + (size_t)gid * 8) = *(const bf16x8*)hb;
        *(bf16x8*)(W2l + (size_t)gid * 8) = *(const bf16x8*)lb;
        return;
    }
    gid -= W2_FRAGS;
    if (gid < WQ_FRAGS) {                         // Wq [256][64], K/32 = 8
        const int l = gid & 63, ks = (gid >> 6) & 7, n16 = gid >> 9;
        const int n = n16 * 16 + (l & 15);
        const int kb = ks * 32 + ((l >> 4) << 3);
        bf16 hb[8], lb[8];
        #pragma unroll
        for (int j = 0; j < 8; ++j)
            split2(Wq[(size_t)(kb + j) * W_DIM + n], hb[j], lb[j]);
        *(bf16x8*)(Wqh + (size_t)gid * 8) = *(const bf16x8*)hb;
        *(bf16x8*)(Wql + (size_t)gid * 8) = *(const bf16x8*)lb;
    }
}

// ---- fused: 32-row strip, whole chain in one block, fragment-direct B ----
// 512 threads = 8 waves. gemm1/2: wave w -> cols 32w..32w+32 (jj = 2 col-frags)
// x 2 row-frags. gemm3: wave w -> row-frag w>>2, col-frag w&3.
// Weight fragments stream from L2 through a depth-3 register ring.
__global__ __launch_bounds__(512) void fused_chain(
    const float* __restrict__ S,
    const bf16* __restrict__ W1h, const bf16* __restrict__ W1l,
    const bf16* __restrict__ W2h, const bf16* __restrict__ W2l,
    const bf16* __restrict__ Wqh, const bf16* __restrict__ Wql,
    const float* __restrict__ b1, const float* __restrict__ b2,
    const float* __restrict__ bq, const float* __restrict__ Wh,
    float* __restrict__ out)
{
    __shared__ bf16 Ssh[32 * LDS_S];        // full 32 x 512 S strip, hi plane
    __shared__ bf16 Ssl[32 * LDS_S];        // lo plane
    __shared__ bf16 E1h[32 * LDE];
    __shared__ bf16 E1l[32 * LDE];
    __shared__ bf16 E2h[32 * LDE];
    __shared__ bf16 E2l[32 * LDE];
    __shared__ float red[2][64];

    const int t = threadIdx.x;
    const int lane = t & 63;
    const int w = t >> 6, quad = lane >> 4, m16 = t & 15;
    const int row0 = blockIdx.x * 32;

    // ---- S strip: issue ALL loads up front; write in k-halves ----
    // per half: 512 threads x 4 float4 = 32 rows x 256 cols fp32.
    // idx2 = i*512 + t -> r = idx2>>6, c = h*256 + (idx2&63)*4 (coalesced).
    float4 va[4], vb[4];
    #pragma unroll
    for (int i = 0; i < 4; ++i) {
        const int idx2 = i * 512 + t;
        const int r = idx2 >> 6, c = (idx2 & 63) << 2;
        va[i] = *(const float4*)(S + (size_t)(row0 + r) * F_IN + c);
    }
    #pragma unroll
    for (int i = 0; i < 4; ++i) {
        const int idx2 = i * 512 + t;
        const int r = idx2 >> 6, c = 256 + ((idx2 & 63) << 2);
        vb[i] = *(const float4*)(S + (size_t)(row0 + r) * F_IN + c);
    }

    // ================= GEMM1: E1 = relu(S @ W1^T + b1) =================
    f32x4 acc[2][2] = {};
    {
        bf16x8 rh[4][2], rl[4][2];                  // depth-3 ring (4 slots)
        #pragma unroll
        for (int p = 0; p < 3; ++p)                 // issued early: latency
            #pragma unroll
            for (int jj = 0; jj < 2; ++jj) {        // drains under S writes
                const size_t off = ((size_t)(((2 * w + jj) * 16 + p) * 64 + lane)) * 8;
                rh[p][jj] = *(const bf16x8*)(W1h + off);
                rl[p][jj] = *(const bf16x8*)(W1l + off);
            }
        // write half 0 (k < 256)
        #pragma unroll
        for (int i = 0; i < 4; ++i) {
            const int idx2 = i * 512 + t;
            const int r = idx2 >> 6, c = (idx2 & 63) << 2;
            bf16 hb[4], lb[4];
            split2(va[i].x, hb[0], lb[0]); split2(va[i].y, hb[1], lb[1]);
            split2(va[i].z, hb[2], lb[2]); split2(va[i].w, hb[3], lb[3]);
            *(bf16x4*)&Ssh[r * LDS_S + c] = *(const bf16x4*)hb;
            *(bf16x4*)&Ssl[r * LDS_S + c] = *(const bf16x4*)lb;
        }
        __syncthreads();                            // half 0 ready
        // write half 1 (k >= 256): disjoint LDS region, no barrier needed yet
        #pragma unroll
        for (int i = 0; i < 4; ++i) {
            const int idx2 = i * 512 + t;
            const int r = idx2 >> 6, c = 256 + ((idx2 & 63) << 2);
            bf16 hb[4], lb[4];
            split2(vb[i].x, hb[0], lb[0]); split2(vb[i].y, hb[1], lb[1]);
            split2(vb[i].z, hb[2], lb[2]); split2(vb[i].w, hb[3], lb[3]);
            *(bf16x4*)&Ssh[r * LDS_S + c] = *(const bf16x4*)hb;
            *(bf16x4*)&Ssl[r * LDS_S + c] = *(const bf16x4*)lb;
        }
        // GEMM1 first half: ks 0..7 (reads k < 256 only)
        #pragma unroll
        for (int ks = 0; ks < 8; ++ks) {
            const int cur = ks & 3;
            {
                const int nx = (ks + 3) & 3;        // prefetch ks+3 (<= 10)
                #pragma unroll
                for (int jj = 0; jj < 2; ++jj) {
                    const size_t off = ((size_t)(((2 * w + jj) * 16 + ks + 3) * 64 + lane)) * 8;
                    rh[nx][jj] = *(const bf16x8*)(W1h + off);
                    rl[nx][jj] = *(const bf16x8*)(W1l + off);
                }
            }
            const int ao = ks * 32 + quad * 8;
            bf16x8 a0h = *(const bf16x8*)&Ssh[m16 * LDS_S + ao];
            bf16x8 a0l = *(const bf16x8*)&Ssl[m16 * LDS_S + ao];
            bf16x8 a1h = *(const bf16x8*)&Ssh[(16 + m16) * LDS_S + ao];
            bf16x8 a1l = *(const bf16x8*)&Ssl[(16 + m16) * LDS_S + ao];
            #pragma unroll
            for (int jj = 0; jj < 2; ++jj) {
                bf16x8 b_h = rh[cur][jj], b_l = rl[cur][jj];
                acc[0][jj] = __builtin_amdgcn_mfma_f32_16x16x32_bf16(a0h, b_h, acc[0][jj], 0, 0, 0);
                acc[0][jj] = __builtin_amdgcn_mfma_f32_16x16x32_bf16(a0l, b_h, acc[0][jj], 0, 0, 0);
                acc[0][jj] = __builtin_amdgcn_mfma_f32_16x16x32_bf16(a0h, b_l, acc[0][jj], 0, 0, 0);
                acc[1][jj] = __builtin_amdgcn_mfma_f32_16x16x32_bf16(a1h, b_h, acc[1][jj], 0, 0, 0);
                acc[1][jj] = __builtin_amdgcn_mfma_f32_16x16x32_bf16(a1l, b_h, acc[1][jj], 0, 0, 0);
                acc[1][jj] = __builtin_amdgcn_mfma_f32_16x16x32_bf16(a1h, b_l, acc[1][jj], 0, 0, 0);
            }
        }
        __syncthreads();                            // half 1 ready
        // GEMM1 second half: ks 8..15
        #pragma unroll
        for (int ks = 8; ks < 16; ++ks) {
            const int cur = ks & 3;
            if (ks + 3 < 16) {
                const int nx = (ks + 3) & 3;
                #pragma unroll
                for (int jj = 0; jj < 2; ++jj) {
                    const size_t off = ((size_t)(((2 * w + jj) * 16 + ks + 3) * 64 + lane)) * 8;
                    rh[nx][jj] = *(const bf16x8*)(W1h + off);
                    rl[nx][jj] = *(const bf16x8*)(W1l + off);
                }
            }
            const int ao = ks * 32 + quad * 8;
            bf16x8 a0h = *(const bf16x8*)&Ssh[m16 * LDS_S + ao];
            bf16x8 a0l = *(const bf16x8*)&Ssl[m16 * LDS_S + ao];
            bf16x8 a1h = *(const bf16x8*)&Ssh[(16 + m16) * LDS_S + ao];
            bf16x8 a1l = *(const bf16x8*)&Ssl[(16 + m16) * LDS_S + ao];
            #pragma unroll
            for (int jj = 0; jj < 2; ++jj) {
                bf16x8 b_h = rh[cur][jj], b_l = rl[cur][jj];
                acc[0][jj] = __builtin_amdgcn_mfma_f32_16x16x32_bf16(a0h, b_h, acc[0][jj], 0, 0, 0);
                acc[0][jj] = __builtin_amdgcn_mfma_f32_16x16x32_bf16(a0l, b_h, acc[0][jj], 0, 0, 0);
                acc[0][jj] = __builtin_amdgcn_mfma_f32_16x16x32_bf16(a0h, b_l, acc[0][jj], 0, 0, 0);
                acc[1][jj] = __builtin_amdgcn_mfma_f32_16x16x32_bf16(a1h, b_h, acc[1][jj], 0, 0, 0);
                acc[1][jj] = __builtin_amdgcn_mfma_f32_16x16x32_bf16(a1l, b_h, acc[1][jj], 0, 0, 0);
                acc[1][jj] = __builtin_amdgcn_mfma_f32_16x16x32_bf16(a1h, b_l, acc[1][jj], 0, 0, 0);
            }
        }
    }
    // epilogue: relu + bias -> E1 hi/lo (LDS)
    #pragma unroll
    for (int i = 0; i < 2; ++i)
        #pragma unroll
        for (int jj = 0; jj < 2; ++jj) {
            const int c = 32 * w + jj * 16 + m16;
            const float bv = b1[c];
            #pragma unroll
            for (int r = 0; r < 4; ++r) {
                const int rr = i * 16 + quad * 4 + r;
                float vv = fmaxf(acc[i][jj][r] + bv, 0.0f);
                split2(vv, E1h[rr * LDE + c], E1l[rr * LDE + c]);
            }
        }

    // ================= GEMM2: E2 = relu(E1 @ W2^T + b2) =================
    {
        bf16x8 rh[4][2], rl[4][2];
        #pragma unroll
        for (int p = 0; p < 3; ++p)                 // hoisted above barrier
            #pragma unroll
            for (int jj = 0; jj < 2; ++jj) {
                const size_t off = ((size_t)(((2 * w + jj) * 8 + p) * 64 + lane)) * 8;
                rh[p][jj] = *(const bf16x8*)(W2h + off);
                rl[p][jj] = *(const bf16x8*)(W2l + off);
            }
        __syncthreads();                            // E1 ready
        #pragma unroll
        for (int i = 0; i < 2; ++i)
            #pragma unroll
            for (int jj = 0; jj < 2; ++jj)
                acc[i][jj] = (f32x4){0.f, 0.f, 0.f, 0.f};
        #pragma unroll
        for (int ks = 0; ks < 8; ++ks) {
            const int cur = ks & 3;
            if (ks + 3 < 8) {
                const int nx = (ks + 3) & 3;
                #pragma unroll
                for (int jj = 0; jj < 2; ++jj) {
                    const size_t off = ((size_t)(((2 * w + jj) * 8 + ks + 3) * 64 + lane)) * 8;
                    rh[nx][jj] = *(const bf16x8*)(W2h + off);
                    rl[nx][jj] = *(const bf16x8*)(W2l + off);
                }
            }
            const int ao = ks * 32 + quad * 8;
            bf16x8 a0h = *(const bf16x8*)&E1h[m16 * LDE + ao];
            bf16x8 a0l = *(const bf16x8*)&E1l[m16 * LDE + ao];
            bf16x8 a1h = *(const bf16x8*)&E1h[(16 + m16) * LDE + ao];
            bf16x8 a1l = *(const bf16x8*)&E1l[(16 + m16) * LDE + ao];
            #pragma unroll
            for (int jj = 0; jj < 2; ++jj) {
                bf16x8 b_h = rh[cur][jj], b_l = rl[cur][jj];
                acc[0][jj] = __builtin_amdgcn_mfma_f32_16x16x32_bf16(a0h, b_h, acc[0][jj], 0, 0, 0);
                acc[0][jj] = __builtin_amdgcn_mfma_f32_16x16x32_bf16(a0l, b_h, acc[0][jj], 0, 0, 0);
                acc[0][jj] = __builtin_amdgcn_mfma_f32_16x16x32_bf16(a0h, b_l, acc[0][jj], 0, 0, 0);
                acc[1][jj] = __builtin_amdgcn_mfma_f32_16x16x32_bf16(a1h, b_h, acc[1][jj], 0, 0, 0);
                acc[1][jj] = __builtin_amdgcn_mfma_f32_16x16x32_bf16(a1l, b_h, acc[1][jj], 0, 0, 0);
                acc[1][jj] = __builtin_amdgcn_mfma_f32_16x16x32_bf16(a1h, b_l, acc[1][jj], 0, 0, 0);
            }
        }
    }
    #pragma unroll
    for (int i = 0; i < 2; ++i)
        #pragma unroll
        for (int jj = 0; jj < 2; ++jj) {
            const int c = 32 * w + jj * 16 + m16;
            const float bv = b2[c];
            #pragma unroll
            for (int r = 0; r < 4; ++r) {
                const int rr = i * 16 + quad * 4 + r;
                float vv = fmaxf(acc[i][jj][r] + bv, 0.0f);
                split2(vv, E2h[rr * LDE + c], E2l[rr * LDE + c]);
            }
        }

    // ====== GEMM3 + tanh + colsum + dot(Wh): atomicAdd one scalar ======
    {
        const int rf = w >> 2, cf = w & 3;
        bf16x8 rh[4], rl[4];
        #pragma unroll
        for (int p = 0; p < 3; ++p) {               // hoisted above barrier
            const size_t off = ((size_t)((cf * 8 + p) * 64 + lane)) * 8;
            rh[p] = *(const bf16x8*)(Wqh + off);
            rl[p] = *(const bf16x8*)(Wql + off);
        }
        __syncthreads();                            // E2 ready
        f32x4 acc3 = {0.f, 0.f, 0.f, 0.f};
        #pragma unroll
        for (int ks = 0; ks < 8; ++ks) {
            const int cur = ks & 3;
            if (ks + 3 < 8) {
                const int nx = (ks + 3) & 3;
                const size_t off = ((size_t)((cf * 8 + ks + 3) * 64 + lane)) * 8;
                rh[nx] = *(const bf16x8*)(Wqh + off);
                rl[nx] = *(const bf16x8*)(Wql + off);
            }
            const int ao = ks * 32 + quad * 8;
            bf16x8 a_h = *(const bf16x8*)&E2h[(rf * 16 + m16) * LDE + ao];
            bf16x8 a_l = *(const bf16x8*)&E2l[(rf * 16 + m16) * LDE + ao];
            acc3 = __builtin_amdgcn_mfma_f32_16x16x32_bf16(a_h, rh[cur], acc3, 0, 0, 0);
            acc3 = __builtin_amdgcn_mfma_f32_16x16x32_bf16(a_l, rh[cur], acc3, 0, 0, 0);
            acc3 = __builtin_amdgcn_mfma_f32_16x16x32_bf16(a_h, rl[cur], acc3, 0, 0, 0);
        }
        const int c = cf * 16 + m16;
        const float bv = bq[c];
        float v = 0.f;
        #pragma unroll
        for (int r = 0; r < 4; ++r)
            v += tanhf(acc3[r] + bv);
        v += __shfl_xor(v, 16, 64);       // sum rows within row-frag
        v += __shfl_xor(v, 32, 64);
        if (quad == 0) red[rf][c] = v;    // (rf,cf) waves write disjoint cols
        __syncthreads();
        if (t < W_DIM) {
            float s = (red[0][t] + red[1][t]) * Wh[t];
            #pragma unroll
            for (int o = 32; o > 0; o >>= 1) s += __shfl_down(s, o);
            if (t == 0) atomicAdd(out, s);
        }
    }
}

extern "C" void kernel_launch(void* const* d_in, const int* in_sizes, int n_in,
                              void* d_out, int out_size, void* d_ws, size_t ws_size,
                              hipStream_t stream) {
    const float* state = (const float*)d_in[0];
    const float* W1    = (const float*)d_in[1];
    const float* b1    = (const float*)d_in[2];
    const float* W2    = (const float*)d_in[3];
    const float* b2    = (const float*)d_in[4];
    const float* Wq    = (const float*)d_in[5];
    const float* bq    = (const float*)d_in[6];
    const float* Wh    = (const float*)d_in[7];
    const float* bh    = (const float*)d_in[8];

    bf16* p = (bf16*)d_ws;
    bf16* W1h = p; p += (size_t)H_DIM * F_IN;
    bf16* W1l = p; p += (size_t)H_DIM * F_IN;
    bf16* W2h = p; p += (size_t)H_DIM * H_DIM;
    bf16* W2l = p; p += (size_t)H_DIM * H_DIM;
    bf16* Wqh = p; p += (size_t)W_DIM * H_DIM;
    bf16* Wql = p; p += (size_t)W_DIM * H_DIM;

    prep_w<<<PREP_BLOCKS, 256, 0, stream>>>(
        W1, W2, Wq, bh, W1h, W1l, W2h, W2l, Wqh, Wql, (float*)d_out);

    fused_chain<<<N_ROWS / 32, 512, 0, stream>>>(
        state, W1h, W1l, W2h, W2l, Wqh, Wql, b1, b2, bq, Wh, (float*)d_out);
}

// Round 5
// 91.728 us; speedup vs baseline: 1.5575x; 1.0215x over previous
//
#include <hip/hip_runtime.h>
#include <hip/hip_bf16.h>
#include <math.h>

// out = colsum( tanh( relu( relu(S@W1+b1)@W2+b2 )@Wq+bq ) ) @ Wh + bh
// (graph stage is a no-op: all edge weights 1.0 => mean_w == 1.0 everywhere)
//
// Round 12: round-11 + (a) 4-chunk S staging pipeline (compute ks-quad i
// overlaps HBM arrival + LDS write of chunk i+1; exposed head ~1 chunk
// instead of ~half the stream) and (b) prep_w split 2 threads/fragment
// (104 -> 208 blocks; latency-bound kernel gets 2x parallelism).
// Same k order / split order / MFMA sequence -> bit-identical, absmax 0.

#define N_ROWS 8192
#define F_IN   512
#define H_DIM  256
#define W_DIM  64

#define LDS_S 520   // S-plane leading dim (bf16): 1040 B stride == 4 banks mod 32 (free)
#define LDE   264   // E-plane leading dim:  528 B stride == 4 banks mod 32 (free)

// fragment-ordered weight planes: frag id = (n16*(K/32) + ks), 64 lanes x 8 bf16
#define W1_FRAGS (16 * 16 * 64)   // n16 x ks x lane threads
#define W2_FRAGS (16 * 8 * 64)
#define WQ_FRAGS (4 * 8 * 64)
// prep: 2 threads per fragment-lane item (j-halves)
#define PREP_T   ((W1_FRAGS + W2_FRAGS + WQ_FRAGS) * 2)
#define PREP_BLOCKS ((PREP_T + 255) / 256)

using bf16x8 = __attribute__((ext_vector_type(8))) short;
using bf16x4 = __attribute__((ext_vector_type(4))) short;
using f32x4  = __attribute__((ext_vector_type(4))) float;
typedef __hip_bfloat16 bf16;

__device__ __forceinline__ void split2(float v, bf16& hi, bf16& lo) {
    bf16 h = __float2bfloat16(v);
    hi = h;
    lo = __float2bfloat16(v - __bfloat162float(h));
}

// ---- weight split + repack into MFMA fragment order; out = bh ----
// layout: plane[((n16*(K/32)+ks)*64+lane)*8+j] = W[ks*32+(lane>>4)*8+j][n16*16+(lane&15)]
// 2 threads per (frag,lane): jh selects j = jh*4 .. jh*4+3 (bf16x4 writes).
__global__ __launch_bounds__(256) void prep_w(
    const float* __restrict__ W1, const float* __restrict__ W2,
    const float* __restrict__ Wq, const float* __restrict__ bh,
    bf16* __restrict__ W1h, bf16* __restrict__ W1l,
    bf16* __restrict__ W2h, bf16* __restrict__ W2l,
    bf16* __restrict__ Wqh, bf16* __restrict__ Wql,
    float* __restrict__ out)
{
    if (blockIdx.x == 0 && threadIdx.x == 0) out[0] = bh[0];
    int tid = blockIdx.x * 256 + threadIdx.x;
    const int jh = tid & 1;            // j-half
    int gid = tid >> 1;                // fragment-lane item
    if (gid < W1_FRAGS) {                         // W1 [512][256], K/32 = 16
        const int l = gid & 63, ks = (gid >> 6) & 15, n16 = gid >> 10;
        const int n = n16 * 16 + (l & 15);
        const int kb = ks * 32 + ((l >> 4) << 3) + jh * 4;
        bf16 hb[4], lb[4];
        #pragma unroll
        for (int j = 0; j < 4; ++j)
            split2(W1[(size_t)(kb + j) * H_DIM + n], hb[j], lb[j]);
        *(bf16x4*)(W1h + (size_t)gid * 8 + jh * 4) = *(const bf16x4*)hb;
        *(bf16x4*)(W1l + (size_t)gid * 8 + jh * 4) = *(const bf16x4*)lb;
        return;
    }
    gid -= W1_FRAGS;
    if (gid < W2_FRAGS) {                         // W2 [256][256], K/32 = 8
        const int l = gid & 63, ks = (gid >> 6) & 7, n16 = gid >> 9;
        const int n = n16 * 16 + (l & 15);
        const int kb = ks * 32 + ((l >> 4) << 3) + jh * 4;
        bf16 hb[4], lb[4];
        #pragma unroll
        for (int j = 0; j < 4; ++j)
            split2(W2[(size_t)(kb + j) * H_DIM + n], hb[j], lb[j]);
        *(bf16x4*)(W2h + (size_t)gid * 8 + jh * 4) = *(const bf16x4*)hb;
        *(bf16x4*)(W2l + (size_t)gid * 8 + jh * 4) = *(const bf16x4*)lb;
        return;
    }
    gid -= W2_FRAGS;
    if (gid < WQ_FRAGS) {                         // Wq [256][64], K/32 = 8
        const int l = gid & 63, ks = (gid >> 6) & 7, n16 = gid >> 9;
        const int n = n16 * 16 + (l & 15);
        const int kb = ks * 32 + ((l >> 4) << 3) + jh * 4;
        bf16 hb[4], lb[4];
        #pragma unroll
        for (int j = 0; j < 4; ++j)
            split2(Wq[(size_t)(kb + j) * W_DIM + n], hb[j], lb[j]);
        *(bf16x4*)(Wqh + (size_t)gid * 8 + jh * 4) = *(const bf16x4*)hb;
        *(bf16x4*)(Wql + (size_t)gid * 8 + jh * 4) = *(const bf16x4*)lb;
    }
}

// ---- fused: 32-row strip, whole chain in one block, fragment-direct B ----
// 512 threads = 8 waves. gemm1/2: wave w -> cols 32w..32w+32 (jj = 2 col-frags)
// x 2 row-frags. gemm3: wave w -> row-frag w>>2, col-frag w&3.
// Weight fragments stream from L2 through a depth-3 register ring.
__global__ __launch_bounds__(512) void fused_chain(
    const float* __restrict__ S,
    const bf16* __restrict__ W1h, const bf16* __restrict__ W1l,
    const bf16* __restrict__ W2h, const bf16* __restrict__ W2l,
    const bf16* __restrict__ Wqh, const bf16* __restrict__ Wql,
    const float* __restrict__ b1, const float* __restrict__ b2,
    const float* __restrict__ bq, const float* __restrict__ Wh,
    float* __restrict__ out)
{
    __shared__ bf16 Ssh[32 * LDS_S];        // full 32 x 512 S strip, hi plane
    __shared__ bf16 Ssl[32 * LDS_S];        // lo plane
    __shared__ bf16 E1h[32 * LDE];
    __shared__ bf16 E1l[32 * LDE];
    __shared__ bf16 E2h[32 * LDE];
    __shared__ bf16 E2l[32 * LDE];
    __shared__ float red[2][64];

    const int t = threadIdx.x;
    const int lane = t & 63;
    const int w = t >> 6, quad = lane >> 4, m16 = t & 15;
    const int row0 = blockIdx.x * 32;

    // ---- S strip: issue ALL loads up front; write/consume in 4 k-chunks ----
    // chunk c covers k in [c*128, c*128+128): 512 threads x 2 float4.
    // idx2 = i*512 + t -> r = idx2>>5, c = cbase + (idx2&31)*4 (coalesced).
    float4 vs[4][2];
    #pragma unroll
    for (int ch = 0; ch < 4; ++ch)
        #pragma unroll
        for (int i = 0; i < 2; ++i) {
            const int idx2 = i * 512 + t;
            const int r = idx2 >> 5, c = ch * 128 + ((idx2 & 31) << 2);
            vs[ch][i] = *(const float4*)(S + (size_t)(row0 + r) * F_IN + c);
        }

#define S_WRITE_CHUNK(ch)                                                     \
    {                                                                         \
        _Pragma("unroll")                                                     \
        for (int i = 0; i < 2; ++i) {                                         \
            const int idx2 = i * 512 + t;                                     \
            const int r = idx2 >> 5, c = (ch) * 128 + ((idx2 & 31) << 2);     \
            bf16 hb[4], lb[4];                                                \
            split2(vs[ch][i].x, hb[0], lb[0]);                                \
            split2(vs[ch][i].y, hb[1], lb[1]);                                \
            split2(vs[ch][i].z, hb[2], lb[2]);                                \
            split2(vs[ch][i].w, hb[3], lb[3]);                                \
            *(bf16x4*)&Ssh[r * LDS_S + c] = *(const bf16x4*)hb;               \
            *(bf16x4*)&Ssl[r * LDS_S + c] = *(const bf16x4*)lb;               \
        }                                                                     \
    }

    // ================= GEMM1: E1 = relu(S @ W1^T + b1) =================
    f32x4 acc[2][2] = {};
    {
        bf16x8 rh[4][2], rl[4][2];                  // depth-3 ring (4 slots)
        #pragma unroll
        for (int p = 0; p < 3; ++p)                 // issued early: latency
            #pragma unroll
            for (int jj = 0; jj < 2; ++jj) {        // drains under S writes
                const size_t off = ((size_t)(((2 * w + jj) * 16 + p) * 64 + lane)) * 8;
                rh[p][jj] = *(const bf16x8*)(W1h + off);
                rl[p][jj] = *(const bf16x8*)(W1l + off);
            }
        S_WRITE_CHUNK(0)
        __syncthreads();                            // chunk 0 ready
        S_WRITE_CHUNK(1)                            // disjoint region: no bar yet

        #pragma unroll
        for (int ks = 0; ks < 16; ++ks) {
            // pipeline barriers: before consuming a new chunk, publish it and
            // pre-write the following one (disjoint LDS -> no barrier needed)
            if (ks == 4) {
                __syncthreads();                    // chunk 1 ready
                S_WRITE_CHUNK(2)
            } else if (ks == 8) {
                __syncthreads();                    // chunk 2 ready
                S_WRITE_CHUNK(3)
            } else if (ks == 12) {
                __syncthreads();                    // chunk 3 ready
            }
            const int cur = ks & 3;
            if (ks + 3 < 16) {
                const int nx = (ks + 3) & 3;
                #pragma unroll
                for (int jj = 0; jj < 2; ++jj) {
                    const size_t off = ((size_t)(((2 * w + jj) * 16 + ks + 3) * 64 + lane)) * 8;
                    rh[nx][jj] = *(const bf16x8*)(W1h + off);
                    rl[nx][jj] = *(const bf16x8*)(W1l + off);
                }
            }
            const int ao = ks * 32 + quad * 8;
            bf16x8 a0h = *(const bf16x8*)&Ssh[m16 * LDS_S + ao];
            bf16x8 a0l = *(const bf16x8*)&Ssl[m16 * LDS_S + ao];
            bf16x8 a1h = *(const bf16x8*)&Ssh[(16 + m16) * LDS_S + ao];
            bf16x8 a1l = *(const bf16x8*)&Ssl[(16 + m16) * LDS_S + ao];
            #pragma unroll
            for (int jj = 0; jj < 2; ++jj) {
                bf16x8 b_h = rh[cur][jj], b_l = rl[cur][jj];
                acc[0][jj] = __builtin_amdgcn_mfma_f32_16x16x32_bf16(a0h, b_h, acc[0][jj], 0, 0, 0);
                acc[0][jj] = __builtin_amdgcn_mfma_f32_16x16x32_bf16(a0l, b_h, acc[0][jj], 0, 0, 0);
                acc[0][jj] = __builtin_amdgcn_mfma_f32_16x16x32_bf16(a0h, b_l, acc[0][jj], 0, 0, 0);
                acc[1][jj] = __builtin_amdgcn_mfma_f32_16x16x32_bf16(a1h, b_h, acc[1][jj], 0, 0, 0);
                acc[1][jj] = __builtin_amdgcn_mfma_f32_16x16x32_bf16(a1l, b_h, acc[1][jj], 0, 0, 0);
                acc[1][jj] = __builtin_amdgcn_mfma_f32_16x16x32_bf16(a1h, b_l, acc[1][jj], 0, 0, 0);
            }
        }
    }
    // epilogue: relu + bias -> E1 hi/lo (LDS)
    #pragma unroll
    for (int i = 0; i < 2; ++i)
        #pragma unroll
        for (int jj = 0; jj < 2; ++jj) {
            const int c = 32 * w + jj * 16 + m16;
            const float bv = b1[c];
            #pragma unroll
            for (int r = 0; r < 4; ++r) {
                const int rr = i * 16 + quad * 4 + r;
                float vv = fmaxf(acc[i][jj][r] + bv, 0.0f);
                split2(vv, E1h[rr * LDE + c], E1l[rr * LDE + c]);
            }
        }

    // ================= GEMM2: E2 = relu(E1 @ W2^T + b2) =================
    {
        bf16x8 rh[4][2], rl[4][2];
        #pragma unroll
        for (int p = 0; p < 3; ++p)                 // hoisted above barrier
            #pragma unroll
            for (int jj = 0; jj < 2; ++jj) {
                const size_t off = ((size_t)(((2 * w + jj) * 8 + p) * 64 + lane)) * 8;
                rh[p][jj] = *(const bf16x8*)(W2h + off);
                rl[p][jj] = *(const bf16x8*)(W2l + off);
            }
        __syncthreads();                            // E1 ready
        #pragma unroll
        for (int i = 0; i < 2; ++i)
            #pragma unroll
            for (int jj = 0; jj < 2; ++jj)
                acc[i][jj] = (f32x4){0.f, 0.f, 0.f, 0.f};
        #pragma unroll
        for (int ks = 0; ks < 8; ++ks) {
            const int cur = ks & 3;
            if (ks + 3 < 8) {
                const int nx = (ks + 3) & 3;
                #pragma unroll
                for (int jj = 0; jj < 2; ++jj) {
                    const size_t off = ((size_t)(((2 * w + jj) * 8 + ks + 3) * 64 + lane)) * 8;
                    rh[nx][jj] = *(const bf16x8*)(W2h + off);
                    rl[nx][jj] = *(const bf16x8*)(W2l + off);
                }
            }
            const int ao = ks * 32 + quad * 8;
            bf16x8 a0h = *(const bf16x8*)&E1h[m16 * LDE + ao];
            bf16x8 a0l = *(const bf16x8*)&E1l[m16 * LDE + ao];
            bf16x8 a1h = *(const bf16x8*)&E1h[(16 + m16) * LDE + ao];
            bf16x8 a1l = *(const bf16x8*)&E1l[(16 + m16) * LDE + ao];
            #pragma unroll
            for (int jj = 0; jj < 2; ++jj) {
                bf16x8 b_h = rh[cur][jj], b_l = rl[cur][jj];
                acc[0][jj] = __builtin_amdgcn_mfma_f32_16x16x32_bf16(a0h, b_h, acc[0][jj], 0, 0, 0);
                acc[0][jj] = __builtin_amdgcn_mfma_f32_16x16x32_bf16(a0l, b_h, acc[0][jj], 0, 0, 0);
                acc[0][jj] = __builtin_amdgcn_mfma_f32_16x16x32_bf16(a0h, b_l, acc[0][jj], 0, 0, 0);
                acc[1][jj] = __builtin_amdgcn_mfma_f32_16x16x32_bf16(a1h, b_h, acc[1][jj], 0, 0, 0);
                acc[1][jj] = __builtin_amdgcn_mfma_f32_16x16x32_bf16(a1l, b_h, acc[1][jj], 0, 0, 0);
                acc[1][jj] = __builtin_amdgcn_mfma_f32_16x16x32_bf16(a1h, b_l, acc[1][jj], 0, 0, 0);
            }
        }
    }
    #pragma unroll
    for (int i = 0; i < 2; ++i)
        #pragma unroll
        for (int jj = 0; jj < 2; ++jj) {
            const int c = 32 * w + jj * 16 + m16;
            const float bv = b2[c];
            #pragma unroll
            for (int r = 0; r < 4; ++r) {
                const int rr = i * 16 + quad * 4 + r;
                float vv = fmaxf(acc[i][jj][r] + bv, 0.0f);
                split2(vv, E2h[rr * LDE + c], E2l[rr * LDE + c]);
            }
        }

    // ====== GEMM3 + tanh + colsum + dot(Wh): atomicAdd one scalar ======
    {
        const int rf = w >> 2, cf = w & 3;
        bf16x8 rh[4], rl[4];
        #pragma unroll
        for (int p = 0; p < 3; ++p) {               // hoisted above barrier
            const size_t off = ((size_t)((cf * 8 + p) * 64 + lane)) * 8;
            rh[p] = *(const bf16x8*)(Wqh + off);
            rl[p] = *(const bf16x8*)(Wql + off);
        }
        __syncthreads();                            // E2 ready
        f32x4 acc3 = {0.f, 0.f, 0.f, 0.f};
        #pragma unroll
        for (int ks = 0; ks < 8; ++ks) {
            const int cur = ks & 3;
            if (ks + 3 < 8) {
                const int nx = (ks + 3) & 3;
                const size_t off = ((size_t)((cf * 8 + ks + 3) * 64 + lane)) * 8;
                rh[nx] = *(const bf16x8*)(Wqh + off);
                rl[nx] = *(const bf16x8*)(Wql + off);
            }
            const int ao = ks * 32 + quad * 8;
            bf16x8 a_h = *(const bf16x8*)&E2h[(rf * 16 + m16) * LDE + ao];
            bf16x8 a_l = *(const bf16x8*)&E2l[(rf * 16 + m16) * LDE + ao];
            acc3 = __builtin_amdgcn_mfma_f32_16x16x32_bf16(a_h, rh[cur], acc3, 0, 0, 0);
            acc3 = __builtin_amdgcn_mfma_f32_16x16x32_bf16(a_l, rh[cur], acc3, 0, 0, 0);
            acc3 = __builtin_amdgcn_mfma_f32_16x16x32_bf16(a_h, rl[cur], acc3, 0, 0, 0);
        }
        const int c = cf * 16 + m16;
        const float bv = bq[c];
        float v = 0.f;
        #pragma unroll
        for (int r = 0; r < 4; ++r)
            v += tanhf(acc3[r] + bv);
        v += __shfl_xor(v, 16, 64);       // sum rows within row-frag
        v += __shfl_xor(v, 32, 64);
        if (quad == 0) red[rf][c] = v;    // (rf,cf) waves write disjoint cols
        __syncthreads();
        if (t < W_DIM) {
            float s = (red[0][t] + red[1][t]) * Wh[t];
            #pragma unroll
            for (int o = 32; o > 0; o >>= 1) s += __shfl_down(s, o);
            if (t == 0) atomicAdd(out, s);
        }
    }
}

extern "C" void kernel_launch(void* const* d_in, const int* in_sizes, int n_in,
                              void* d_out, int out_size, void* d_ws, size_t ws_size,
                              hipStream_t stream) {
    const float* state = (const float*)d_in[0];
    const float* W1    = (const float*)d_in[1];
    const float* b1    = (const float*)d_in[2];
    const float* W2    = (const float*)d_in[3];
    const float* b2    = (const float*)d_in[4];
    const float* Wq    = (const float*)d_in[5];
    const float* bq    = (const float*)d_in[6];
    const float* Wh    = (const float*)d_in[7];
    const float* bh    = (const float*)d_in[8];

    bf16* p = (bf16*)d_ws;
    bf16* W1h = p; p += (size_t)H_DIM * F_IN;
    bf16* W1l = p; p += (size_t)H_DIM * F_IN;
    bf16* W2h = p; p += (size_t)H_DIM * H_DIM;
    bf16* W2l = p; p += (size_t)H_DIM * H_DIM;
    bf16* Wqh = p; p += (size_t)W_DIM * H_DIM;
    bf16* Wql = p; p += (size_t)W_DIM * H_DIM;

    prep_w<<<PREP_BLOCKS, 256, 0, stream>>>(
        W1, W2, Wq, bh, W1h, W1l, W2h, W2l, Wqh, Wql, (float*)d_out);

    fused_chain<<<N_ROWS / 32, 512, 0, stream>>>(
        state, W1h, W1l, W2h, W2l, Wqh, Wql, b1, b2, bq, Wh, (float*)d_out);
}